// Round 1
// baseline (92.107 us; speedup 1.0000x reference)
//
#include <hip/hip_runtime.h>
#include <math.h>

// ROI max-pooling, mirrors the JAX reference exactly.
// Shapes fixed by the problem: features [B,256,64,64] f32, rois [N,5] f32.
// Output layout (flat f32): out[N*C*49] then bid[N].

#define POOL 7
#define CCH  256   // channels (pow2 -> task/C is a shift)
#define FH   64
#define FW   64
#define WAVES_PER_BLOCK 4

__global__ __launch_bounds__(256) void roipool_kernel(
    const float* __restrict__ feat,   // [B, C, H, W]
    const float* __restrict__ rois,   // [N, 5]
    float* __restrict__ out,          // [N*C*49 + N]
    int N)
{
    // Per-wave column-max staging; inner dim padded 64->65 so that the
    // phase-2 reads (7 lanes per ph hitting the same l) land in distinct banks.
    __shared__ float smem[WAVES_PER_BLOCK][POOL][65];

    const int wave = threadIdx.x >> 6;
    const int lane = threadIdx.x & 63;
    int task = blockIdx.x * WAVES_PER_BLOCK + wave;
    const int ntask = N * CCH;
    if (task >= ntask) task = ntask - 1;   // duplicate work; identical dup writes are benign
    const int n = task >> 8;               // task / 256
    const int c = task & (CCH - 1);

    // ROI decode (uniform across the wave; 5 broadcast loads)
    const float* r = rois + (size_t)n * 5;
    const int b  = (int)r[0];
    int px = __float2int_rn(r[1] * 0.0625f);
    int py = __float2int_rn(r[2] * 0.0625f);
    int qx = __float2int_rn(r[3] * 0.0625f);
    int qy = __float2int_rn(r[4] * 0.0625f);
    px = min(max(px, 0), FW - 1); qx = min(max(qx, 0), FW - 1);
    py = min(max(py, 0), FH - 1); qy = min(max(qy, 0), FH - 1);

    const int len_c = max(qx - px + 1, 1);
    const int psz_c = (len_c + POOL - 1) / POOL;   // cells per col-bin
    const int pad_c = (psz_c * POOL - len_c) >> 1; // leading zero-pad (cols)
    const int len_r = max(qy - py + 1, 1);
    const int psz_r = (len_r + POOL - 1) / POOL;
    const int pad_r = (psz_r * POOL - len_r) >> 1;

    const float NEG = -__builtin_huge_valf();

    // Lane -> feature column. Inactive lanes (lane >= len_c) load a clamped
    // in-range duplicate column; phase 2 never reads their smem slots.
    const float* base = feat + ((size_t)(b * CCH + c)) * (FH * FW);
    const int col = px + min(lane, len_c - 1);

    // Phase 1: per row-bin ph, running max over that bin's rows (coalesced
    // 64-lane row loads, contiguous in W).
    #pragma unroll
    for (int ph = 0; ph < POOL; ++ph) {
        const int r0 = max(py, py - pad_r + ph * psz_r);
        const int r1 = min(qy, py - pad_r + (ph + 1) * psz_r - 1);
        float mm = NEG;                      // empty bin stays -inf -> 0 later
        for (int rr = r0; rr <= r1; ++rr)
            mm = fmaxf(mm, base[rr * FW + col]);
        smem[wave][ph][lane] = mm;
    }
    __syncthreads();

    // Phase 2: 49 lanes each reduce one (ph, pw) bin over its column span.
    if (lane < POOL * POOL) {
        const int ph = lane / POOL;
        const int pw = lane - ph * POOL;
        const int l0 = max(0, pw * psz_c - pad_c);
        const int l1 = min(len_c - 1, (pw + 1) * psz_c - 1 - pad_c);
        float v = NEG;
        for (int l = l0; l <= l1; ++l)
            v = fmaxf(v, smem[wave][ph][l]);
        // Bins touching zero-padding compete with 0 (covers empty bins too).
        const bool hp = (ph * psz_r < pad_r) | ((ph + 1) * psz_r > pad_r + len_r)
                      | (pw * psz_c < pad_c) | ((pw + 1) * psz_c > pad_c + len_c);
        if (hp) v = fmaxf(v, 0.0f);
        if (!isfinite(v)) v = 0.0f;          // fully-padded (empty) bins -> 0
        out[((size_t)n * CCH + c) * (POOL * POOL) + lane] = v;
    } else if (lane == POOL * POOL && c == 0) {
        // Second tuple output: bid[N], written as f32 values.
        out[(size_t)N * CCH * (POOL * POOL) + n] = (float)b;
    }
}

extern "C" void kernel_launch(void* const* d_in, const int* in_sizes, int n_in,
                              void* d_out, int out_size, void* d_ws, size_t ws_size,
                              hipStream_t stream) {
    const float* feat = (const float*)d_in[0];
    const float* rois = (const float*)d_in[1];
    float* out = (float*)d_out;
    const int N = in_sizes[1] / 5;           // 128
    const int ntask = N * CCH;               // one wave per (roi, channel)
    const int blocks = (ntask + WAVES_PER_BLOCK - 1) / WAVES_PER_BLOCK;
    roipool_kernel<<<blocks, 64 * WAVES_PER_BLOCK, 0, stream>>>(feat, rois, out, N);
}

// Round 2
// 85.997 us; speedup vs baseline: 1.0711x; 1.0711x over previous
//
#include <hip/hip_runtime.h>
#include <math.h>

// ROI max-pooling, mirrors the JAX reference exactly.
// Shapes fixed by the problem: features [B,256,64,64] f32, rois [N,5] f32.
// Output layout (flat f32): out[N*C*49] then bid[N] (as f32 values).
//
// R2 structure: one wave per (roi, channel). Phase 1 walks the ROI's rows
// ONCE in order (bin boundaries are wave-uniform scalars -> scalar branches),
// issuing 4 independent coalesced 256 B row loads per iteration so load
// latency pipelines, instead of R1's 7 serialized per-bin load->fmax chains.

#define POOL 7
#define CCH  256   // channels (pow2 -> task/C is a shift)
#define FH   64
#define FW   64
#define WAVES_PER_BLOCK 4

__global__ __launch_bounds__(256) void roipool_kernel(
    const float* __restrict__ feat,   // [B, C, H, W]
    const float* __restrict__ rois,   // [N, 5]
    float* __restrict__ out,          // [N*C*49 + N]
    int N)
{
    // Per-wave column-max staging; inner dim padded 64->65 to spread the
    // phase-2 reads across banks. Each wave only touches its own slice.
    __shared__ float smem[WAVES_PER_BLOCK][POOL][65];

    const int wave = threadIdx.x >> 6;
    const int lane = threadIdx.x & 63;
    int task = blockIdx.x * WAVES_PER_BLOCK + wave;
    const int ntask = N * CCH;
    if (task >= ntask) task = ntask - 1;   // duplicate work; identical writes are benign
    const int n = task >> 8;               // task / 256
    const int c = task & (CCH - 1);

    // ROI decode (uniform across the wave)
    const float* r = rois + (size_t)n * 5;
    const int b  = (int)r[0];
    int px = __float2int_rn(r[1] * 0.0625f);
    int py = __float2int_rn(r[2] * 0.0625f);
    int qx = __float2int_rn(r[3] * 0.0625f);
    int qy = __float2int_rn(r[4] * 0.0625f);
    px = min(max(px, 0), FW - 1); qx = min(max(qx, 0), FW - 1);
    py = min(max(py, 0), FH - 1); qy = min(max(qy, 0), FH - 1);

    const int len_c = max(qx - px + 1, 1);
    const int psz_c = (len_c + POOL - 1) / POOL;   // cells per col-bin
    const int pad_c = (psz_c * POOL - len_c) >> 1; // leading zero-pad (cols)
    const int len_r = max(qy - py + 1, 1);
    const int psz_r = (len_r + POOL - 1) / POOL;
    const int pad_r = (psz_r * POOL - len_r) >> 1;

    const float NEG = -__builtin_huge_valf();

    // Empty (fully-padded) row bins must end up NEG -> 0 in phase 2.
    #pragma unroll
    for (int i = 0; i < POOL; ++i)
        smem[wave][i][lane] = NEG;

    // Lane -> feature column. Lanes >= len_c load a clamped in-range duplicate
    // column; phase 2 never reads their smem slots.
    const float* base = feat + ((size_t)(b * CCH + c)) * (FH * FW);
    const float* basecol = base + (px + min(lane, len_c - 1));

    // Phase 1: single ordered row walk. Bin of row rr is (rr-py+pad_r)/psz_r;
    // rows of one bin are consecutive, so we keep one running max and close
    // the bin at its (wave-uniform) end row. 4 independent loads per chunk.
    int ph = pad_r / psz_r;                          // bin containing row py
    int e  = py - pad_r + (ph + 1) * psz_r - 1;      // last row of bin ph
    float mm = NEG;

    auto step = [&](int rrk, float v) {
        if (rrk > qy) return;                        // uniform tail mask
        mm = fmaxf(mm, v);
        if (rrk >= e || rrk == qy) {                 // close bin (ph <= 6 here)
            smem[wave][ph][lane] = mm;
            mm = NEG; ++ph; e += psz_r;
        }
    };

    for (int rr = py; rr <= qy; rr += 4) {
        // Clamped addresses stay in range; tail values discarded by step().
        float v0 = basecol[rr * FW];
        float v1 = basecol[min(rr + 1, qy) * FW];
        float v2 = basecol[min(rr + 2, qy) * FW];
        float v3 = basecol[min(rr + 3, qy) * FW];
        step(rr,     v0);
        step(rr + 1, v1);
        step(rr + 2, v2);
        step(rr + 3, v3);
    }

    __syncthreads();   // compiler-level LDS ordering fence (intra-wave reads)

    // Phase 2: 49 lanes each reduce one (ph, pw) bin over its column span.
    if (lane < POOL * POOL) {
        const int bh = lane / POOL;
        const int pw = lane - bh * POOL;
        const int l0 = max(0, pw * psz_c - pad_c);
        const int l1 = min(len_c - 1, (pw + 1) * psz_c - 1 - pad_c);
        float v = NEG;
        for (int l = l0; l <= l1; ++l)
            v = fmaxf(v, smem[wave][bh][l]);
        // Bins touching zero-padding compete with 0 (covers empty bins too).
        const bool hp = (bh * psz_r < pad_r) | ((bh + 1) * psz_r > pad_r + len_r)
                      | (pw * psz_c < pad_c) | ((pw + 1) * psz_c > pad_c + len_c);
        if (hp) v = fmaxf(v, 0.0f);
        if (!isfinite(v)) v = 0.0f;          // fully-padded (empty) bins -> 0
        out[((size_t)n * CCH + c) * (POOL * POOL) + lane] = v;
    } else if (lane == POOL * POOL && c == 0) {
        // Second tuple output: bid[N], written as f32 values.
        out[(size_t)N * CCH * (POOL * POOL) + n] = (float)b;
    }
}

extern "C" void kernel_launch(void* const* d_in, const int* in_sizes, int n_in,
                              void* d_out, int out_size, void* d_ws, size_t ws_size,
                              hipStream_t stream) {
    const float* feat = (const float*)d_in[0];
    const float* rois = (const float*)d_in[1];
    float* out = (float*)d_out;
    const int N = in_sizes[1] / 5;           // 128
    const int ntask = N * CCH;               // one wave per (roi, channel)
    const int blocks = (ntask + WAVES_PER_BLOCK - 1) / WAVES_PER_BLOCK;
    roipool_kernel<<<blocks, 64 * WAVES_PER_BLOCK, 0, stream>>>(feat, rois, out, N);
}

// Round 3
// 81.256 us; speedup vs baseline: 1.1335x; 1.0583x over previous
//
#include <hip/hip_runtime.h>
#include <math.h>

// ROI max-pooling, mirrors the JAX reference exactly.
// features [B=4,C=256,H=64,W=64] f32, rois [N=128,5] f32.
// Output (flat f32): out[N*C*49] then bid[N] (as f32 values).
//
// R3: one wave per (roi, channel-PAIR). Phase 1 walks rows once in order with
// 8 independent coalesced loads per 4-row chunk (2 channel planes), doubling
// memory-level parallelism and halving the wave count (2 residency batches
// instead of 4) -- the kernel is latency-bound, not BW-bound (~184 MB L2
// traffic => 5.3 us floor; measured ~40 us).

#define POOL 7
#define CCH  256   // channels (pow2)
#define FH   64
#define FW   64
#define WPB  4     // waves per block

__global__ __launch_bounds__(256) void roipool_kernel(
    const float* __restrict__ feat,   // [B, C, H, W]
    const float* __restrict__ rois,   // [N, 5]
    float* __restrict__ out,          // [N*C*49 + N]
    int N)
{
    // Per-wave, per-channel column-max staging; inner dim padded 64->65.
    __shared__ float smem[WPB][2][POOL][65];

    const int wave = threadIdx.x >> 6;
    const int lane = threadIdx.x & 63;
    int task = blockIdx.x * WPB + wave;
    const int ntask = N * (CCH / 2);       // one wave = one roi x two channels
    if (task >= ntask) task = ntask - 1;   // duplicate work; identical writes benign
    const int n  = task >> 7;              // / (CCH/2)
    const int c0 = (task & (CCH / 2 - 1)) << 1;

    // ROI decode (uniform across the wave)
    const float* r = rois + (size_t)n * 5;
    const int b  = (int)r[0];
    int px = __float2int_rn(r[1] * 0.0625f);
    int py = __float2int_rn(r[2] * 0.0625f);
    int qx = __float2int_rn(r[3] * 0.0625f);
    int qy = __float2int_rn(r[4] * 0.0625f);
    px = min(max(px, 0), FW - 1); qx = min(max(qx, 0), FW - 1);
    py = min(max(py, 0), FH - 1); qy = min(max(qy, 0), FH - 1);

    const int len_c = max(qx - px + 1, 1);
    const int psz_c = (len_c + POOL - 1) / POOL;
    const int pad_c = (psz_c * POOL - len_c) >> 1;
    const int len_r = max(qy - py + 1, 1);
    const int psz_r = (len_r + POOL - 1) / POOL;
    const int pad_r = (psz_r * POOL - len_r) >> 1;

    const float NEG = -__builtin_huge_valf();

    // Empty (fully-padded) row bins must end up NEG -> 0 in phase 2.
    #pragma unroll
    for (int i = 0; i < POOL; ++i) {
        smem[wave][0][i][lane] = NEG;
        smem[wave][1][i][lane] = NEG;
    }

    // Lane -> feature column (clamped duplicate for lanes >= len_c; phase 2
    // never reads their smem slots, and duplicates hit the same cache line).
    const int colofs = px + min(lane, len_c - 1);
    const float* base0 = feat + ((size_t)(b * CCH + c0)) * (FH * FW) + colofs;
    const float* base1 = base0 + FH * FW;

    // Phase 1: single ordered row walk; bins are consecutive row ranges, so
    // keep running maxes and close a bin at its end row. 8 independent loads
    // per 4-row chunk (2 channels) keep the memory pipe full.
    int ph = pad_r / psz_r;                          // bin containing row py
    int e  = py - pad_r + (ph + 1) * psz_r - 1;      // last row of bin ph
    float m0 = NEG, m1 = NEG;

    auto step = [&](int rrk, float a, float bb) {
        if (rrk > qy) return;                        // tail mask
        m0 = fmaxf(m0, a);
        m1 = fmaxf(m1, bb);
        if (rrk >= e || rrk == qy) {                 // close bin
            smem[wave][0][ph][lane] = m0;
            smem[wave][1][ph][lane] = m1;
            m0 = NEG; m1 = NEG; ++ph; e += psz_r;
        }
    };

    for (int rr = py; rr <= qy; rr += 4) {
        const int o0 = rr * FW;
        const int o1 = min(rr + 1, qy) * FW;
        const int o2 = min(rr + 2, qy) * FW;
        const int o3 = min(rr + 3, qy) * FW;
        float a0 = base0[o0], a1 = base0[o1], a2 = base0[o2], a3 = base0[o3];
        float b0 = base1[o0], b1 = base1[o1], b2 = base1[o2], b3 = base1[o3];
        step(rr,     a0, b0);
        step(rr + 1, a1, b1);
        step(rr + 2, a2, b2);
        step(rr + 3, a3, b3);
    }

    __syncthreads();

    // Phase 2: 49 lanes each reduce one (ph, pw) bin's column span, x2 channels.
    if (lane < POOL * POOL) {
        const int bh = lane / POOL;
        const int pw = lane - bh * POOL;
        const int l0 = max(0, pw * psz_c - pad_c);
        const int l1 = min(len_c - 1, (pw + 1) * psz_c - 1 - pad_c);
        const bool hp = (bh * psz_r < pad_r) | ((bh + 1) * psz_r > pad_r + len_r)
                      | (pw * psz_c < pad_c) | ((pw + 1) * psz_c > pad_c + len_c);
        #pragma unroll
        for (int ch = 0; ch < 2; ++ch) {
            float v = NEG;
            for (int l = l0; l <= l1; ++l)
                v = fmaxf(v, smem[wave][ch][bh][l]);
            if (hp) v = fmaxf(v, 0.0f);              // pad cells compete with 0
            if (!isfinite(v)) v = 0.0f;              // empty bins -> 0
            out[((size_t)n * CCH + c0 + ch) * (POOL * POOL) + lane] = v;
        }
    } else if (lane == POOL * POOL && c0 == 0) {
        // Second tuple output: bid[N], written as f32 values.
        out[(size_t)N * CCH * (POOL * POOL) + n] = (float)b;
    }
}

extern "C" void kernel_launch(void* const* d_in, const int* in_sizes, int n_in,
                              void* d_out, int out_size, void* d_ws, size_t ws_size,
                              hipStream_t stream) {
    const float* feat = (const float*)d_in[0];
    const float* rois = (const float*)d_in[1];
    float* out = (float*)d_out;
    const int N = in_sizes[1] / 5;            // 128
    const int ntask = N * (CCH / 2);          // one wave per (roi, channel pair)
    const int blocks = (ntask + WPB - 1) / WPB;
    roipool_kernel<<<blocks, 64 * WPB, 0, stream>>>(feat, rois, out, N);
}